// Round 1
// baseline (388.970 us; speedup 1.0000x reference)
//
#include <hip/hip_runtime.h>
#include <float.h>

#define IGNORE_INDEX 255

constexpr int N_IMG = 8;
constexpr int C     = 80;     // num_class * cnum
constexpr int HW    = 65536;  // 256*256
constexpr int NC    = 20;     // num_class
constexpr int CNUM  = 4;
constexpr int P     = 8192;   // parcel segments
constexpr int NPIX  = N_IMG * HW;  // 524288
constexpr int STRIPES = 4;
constexpr int NCH   = N_IMG * C;   // 640

// ---- sort-path workspace layout (bytes) ----
// dmall: coalesced per-pixel 20-float rows (written in pixel order, gathered
//        by parcel via sidx). sidx: sorted pixel-id CSR payload (2MB, L2-res).
constexpr size_t B_DM    = 0;                                 // NPIX*20*4
constexpr size_t B_SIDX  = (size_t)NPIX * 20 * 4;             // 41943040
constexpr size_t B_CNT   = B_SIDX + (size_t)NPIX * 4;         // 44040192, 16B aligned
constexpr size_t B_ACC   = B_CNT + (size_t)P * 4;             // memset covers CNT+ACC
constexpr size_t B_OFF   = B_ACC + 64;
constexpr size_t B_WOFF  = B_OFF + (size_t)P * 4;
constexpr size_t B_PM    = B_WOFF + (size_t)P * 4;
constexpr size_t B_PS    = B_PM + (size_t)NCH * STRIPES * 4;
constexpr size_t B_CHOFF = B_PS + (size_t)NCH * STRIPES * 4;
constexpr size_t B_TGT   = B_CHOFF + (size_t)NCH * 4;
constexpr size_t NEED    = B_TGT + (size_t)P * 4;             // ~44.2 MB

__device__ __forceinline__ float waveMax(float v) {
#pragma unroll
  for (int o = 32; o > 0; o >>= 1) v = fmaxf(v, __shfl_down(v, o, 64));
  return v;
}
__device__ __forceinline__ float waveSum(float v) {
#pragma unroll
  for (int o = 32; o > 0; o >>= 1) v += __shfl_down(v, o, 64);
  return v;
}

// K1: blocks [0, 2560): per-(channel,stripe) softmax partial stats.
//     SINGLE memory pass: each thread's 64 floats live in 16 float4 VGPRs;
//     max pass and exp-sum pass run from registers (bit-identical numerics
//     to the old two-pass version, minus the L2-thrashed re-read).
//     blocks [2560, 3072): parcel histogram (rides along).
__global__ __launch_bounds__(256) void stats_hist_kernel(
    const float* __restrict__ f, const int* __restrict__ target,
    const int* __restrict__ parcel, float* __restrict__ pm,
    float* __restrict__ ps, int* __restrict__ cnt) {
  if (blockIdx.x >= NCH * STRIPES) {
    const int t4 = (blockIdx.x - NCH * STRIPES) * 256 + threadIdx.x;
    const int4 tv = ((const int4*)target)[t4];
    const int4 pv = ((const int4*)parcel)[t4];
    if (tv.x != IGNORE_INDEX) atomicAdd(&cnt[pv.x], 1);
    if (tv.y != IGNORE_INDEX) atomicAdd(&cnt[pv.y], 1);
    if (tv.z != IGNORE_INDEX) atomicAdd(&cnt[pv.z], 1);
    if (tv.w != IGNORE_INDEX) atomicAdd(&cnt[pv.w], 1);
    return;
  }
  const int ch = blockIdx.x >> 2, stripe = blockIdx.x & 3;
  const float4* base =
      (const float4*)(f + (size_t)ch * HW + (size_t)stripe * (HW / STRIPES));
  // n4 = HW/STRIPES/4 = 4096 float4s; 16 per thread, held in registers.
  float4 r[16];
#pragma unroll
  for (int i = 0; i < 16; i++) r[i] = base[threadIdx.x + (i << 8)];
  float m = -FLT_MAX;
#pragma unroll
  for (int i = 0; i < 16; i++)
    m = fmaxf(m, fmaxf(fmaxf(r[i].x, r[i].y), fmaxf(r[i].z, r[i].w)));
  __shared__ float sred[4];
  __shared__ float bcast;
  const int wid = threadIdx.x >> 6, lid = threadIdx.x & 63;
  float wm = waveMax(m);
  if (lid == 0) sred[wid] = wm;
  __syncthreads();
  if (threadIdx.x == 0)
    bcast = fmaxf(fmaxf(sred[0], sred[1]), fmaxf(sred[2], sred[3]));
  __syncthreads();
  const float M = bcast;
  float s = 0.f;
#pragma unroll
  for (int i = 0; i < 16; i++)
    s += __expf(r[i].x - M) + __expf(r[i].y - M) + __expf(r[i].z - M) +
         __expf(r[i].w - M);
  float wsv = waveSum(s);
  __syncthreads();
  if (lid == 0) sred[wid] = wsv;
  __syncthreads();
  if (threadIdx.x == 0) {
    pm[blockIdx.x] = M;
    ps[blockIdx.x] = sred[0] + sred[1] + sred[2] + sred[3];
  }
}

// K2: one block of 1024: combine stripe stats (threads < 640) + exclusive
//     scan of cnt[8192] -> offs, woff.
__global__ __launch_bounds__(1024) void combine_scan_kernel(
    const float* __restrict__ pm, const float* __restrict__ ps,
    float* __restrict__ choff, const int* __restrict__ cnt,
    int* __restrict__ offs, int* __restrict__ woff) {
  const int t = threadIdx.x;
  if (t < NCH) {
    float m = -FLT_MAX;
#pragma unroll
    for (int i = 0; i < STRIPES; i++) m = fmaxf(m, pm[t * STRIPES + i]);
    float s = 0.f;
#pragma unroll
    for (int i = 0; i < STRIPES; i++)
      s += ps[t * STRIPES + i] * __expf(pm[t * STRIPES + i] - m);
    choff[t] = m + logf(s);
  }
  __shared__ int sh[1024];
  const int4* c4 = (const int4*)(cnt + t * 8);
  int4 a = c4[0], b = c4[1];
  int c[8] = {a.x, a.y, a.z, a.w, b.x, b.y, b.z, b.w};
  int tot = 0;
#pragma unroll
  for (int j = 0; j < 8; j++) tot += c[j];
  sh[t] = tot;
  __syncthreads();
  for (int d = 1; d < 1024; d <<= 1) {
    int v = (t >= d) ? sh[t - d] : 0;
    __syncthreads();
    sh[t] += v;
    __syncthreads();
  }
  int e = sh[t] - tot;
#pragma unroll
  for (int j = 0; j < 8; j++) {
    offs[t * 8 + j] = e;
    woff[t * 8 + j] = e;
    e += c[j];
  }
}

__device__ __forceinline__ float4 max4(float4 a, float4 b) {
  return make_float4(fmaxf(a.x, b.x), fmaxf(a.y, b.y), fmaxf(a.z, b.z),
                     fmaxf(a.w, b.w));
}

// K3: 4 pixels per thread (all feature loads are float4 / 16B-per-lane).
//     Per-pixel group-max rows are written COALESCED in pixel order to
//     dmall[pg][20]; only the 4-byte pixel id is scattered (sidx[pos]=pg).
//     Also accumulates the diversity term. tgtp via plain store (labels are
//     parcel-constant; any valid writer gives segment_max).
__global__ __launch_bounds__(256) void divbd_scatter_kernel(
    const float* __restrict__ f, const int* __restrict__ target,
    const int* __restrict__ parcel, const float* __restrict__ choff,
    int* __restrict__ woff, float* __restrict__ dmall, int* __restrict__ sidx,
    int* __restrict__ tgtp, float* __restrict__ div_acc) {
  const int tid = blockIdx.x * 256 + threadIdx.x;  // 0..131071
  const int img = tid >> 14;                       // 16384 threads per image
  const int pix0 = (tid & 16383) << 2;
  const float* fb = f + (size_t)img * C * HW + pix0;
  __shared__ float soff[C];
  if (threadIdx.x < C) soff[threadIdx.x] = choff[img * C + threadIdx.x];
  __syncthreads();
  const int pgbase = (img << 16) + pix0;
  float divs = 0.f;
#pragma unroll
  for (int kc = 0; kc < 5; kc++) {
    float4 dmg[4];  // group (kc*4+g) max, components = 4 pixels
#pragma unroll
    for (int g = 0; g < 4; g++) {
      const int k = kc * 4 + g;
      float4 d = make_float4(-FLT_MAX, -FLT_MAX, -FLT_MAX, -FLT_MAX);
      float4 e = make_float4(-FLT_MAX, -FLT_MAX, -FLT_MAX, -FLT_MAX);
#pragma unroll
      for (int j = 0; j < CNUM; j++) {
        const int ch = k * CNUM + j;
        float4 v = *(const float4*)(fb + (size_t)ch * HW);
        const float off = soff[ch];
        d = max4(d, v);
        e = max4(e, make_float4(v.x - off, v.y - off, v.z - off, v.w - off));
      }
      dmg[g] = d;
      divs += __expf(e.x) + __expf(e.y) + __expf(e.z) + __expf(e.w);
    }
    // transpose 4x4 in registers; rows pgbase..pgbase+3, chunk kc
    float4* ob = (float4*)dmall + (size_t)pgbase * 5 + kc;
    ob[0]  = make_float4(dmg[0].x, dmg[1].x, dmg[2].x, dmg[3].x);
    ob[5]  = make_float4(dmg[0].y, dmg[1].y, dmg[2].y, dmg[3].y);
    ob[10] = make_float4(dmg[0].z, dmg[1].z, dmg[2].z, dmg[3].z);
    ob[15] = make_float4(dmg[0].w, dmg[1].w, dmg[2].w, dmg[3].w);
  }
  const int4 tv = *(const int4*)(target + pgbase);
  const int4 pv = *(const int4*)(parcel + pgbase);
  const int ts[4] = {tv.x, tv.y, tv.z, tv.w};
  const int pa[4] = {pv.x, pv.y, pv.z, pv.w};
#pragma unroll
  for (int r = 0; r < 4; r++) {
    if (ts[r] != IGNORE_INDEX) {
      const int pos = atomicAdd(&woff[pa[r]], 1);
      sidx[pos] = pgbase + r;
      tgtp[pa[r]] = ts[r];
    }
  }
  __shared__ float sred[4];
  const int wid = threadIdx.x >> 6, lid = threadIdx.x & 63;
  float wsum = waveSum(divs);
  if (lid == 0) sred[wid] = wsum;
  __syncthreads();
  if (threadIdx.x == 0)
    atomicAdd(div_acc, sred[0] + sred[1] + sred[2] + sred[3]);
}

// K4: one wave per parcel: coalesced read of its sidx slice, then 80B row
//     gathers from dmall (41.9MB, freshly written -> L2/L3 resident).
__global__ __launch_bounds__(256) void parcel_kernel(
    const float* __restrict__ dmall, const int* __restrict__ cnt,
    const int* __restrict__ offs, const int* __restrict__ sidx,
    const int* __restrict__ tgtp, float* __restrict__ acc) {
  const int wid = threadIdx.x >> 6, lid = threadIdx.x & 63;
  const int p = blockIdx.x * 4 + wid;
  const int c = cnt[p];
  float sums[NC];
#pragma unroll
  for (int k = 0; k < NC; k++) sums[k] = 0.f;
  if (c > 0) {
    const int start = offs[p];
    for (int i = lid; i < c; i += 64) {
      const int pg = sidx[start + i];
      const float4* b = (const float4*)dmall + (size_t)pg * 5;
      float4 b0 = b[0], b1 = b[1], b2 = b[2], b3 = b[3], b4 = b[4];
      sums[0] += b0.x;  sums[1] += b0.y;  sums[2] += b0.z;  sums[3] += b0.w;
      sums[4] += b1.x;  sums[5] += b1.y;  sums[6] += b1.z;  sums[7] += b1.w;
      sums[8] += b2.x;  sums[9] += b2.y;  sums[10] += b2.z; sums[11] += b2.w;
      sums[12] += b3.x; sums[13] += b3.y; sums[14] += b3.z; sums[15] += b3.w;
      sums[16] += b4.x; sums[17] += b4.y; sums[18] += b4.z; sums[19] += b4.w;
    }
  }
#pragma unroll
  for (int o = 32; o > 0; o >>= 1) {
#pragma unroll
    for (int k = 0; k < NC; k++) sums[k] += __shfl_xor(sums[k], o, 64);
  }
  float nll = 0.f, val = 0.f;
  if (c > 0) {
    const float inv = 1.f / (float)c;
    float mean[NC];
    float m = -FLT_MAX;
#pragma unroll
    for (int k = 0; k < NC; k++) {
      mean[k] = sums[k] * inv;
      m = fmaxf(m, mean[k]);
    }
    float se = 0.f;
#pragma unroll
    for (int k = 0; k < NC; k++) se += __expf(mean[k] - m);
    const float lse = m + logf(se);
    const int t = min(max(tgtp[p], 0), NC - 1);
    nll = lse - mean[t];
    val = 1.f;
  }
  __shared__ float sn[4], sv[4];
  if (lid == 0) { sn[wid] = nll; sv[wid] = val; }
  __syncthreads();
  if (threadIdx.x == 0) {
    atomicAdd(&acc[1], sn[0] + sn[1] + sn[2] + sn[3]);
    atomicAdd(&acc[2], sv[0] + sv[1] + sv[2] + sv[3]);
  }
}

// K5: scalars out. acc: [0]=div_sum [1]=nll_sum [2]=valid_cnt
__global__ void finalize_kernel(const float* __restrict__ acc,
                                float* __restrict__ out) {
  out[0] = acc[1] / fmaxf(acc[2], 1.f);
  out[1] = 1.f - acc[0] / (float)(N_IMG * NC * NC);
}

// ================= fallback path (R1 code, needs ~723KB ws) =================
constexpr size_t OFF_SEGSUM = 0;
constexpr size_t OFF_COUNTS = 163840;
constexpr size_t OFF_CHOFF  = 172032;
constexpr size_t OFF_ACC    = 172672;
constexpr size_t BYTE_TGT   = 690752;
constexpr size_t BYTE_ZERO  = 690752;
constexpr size_t BYTE_TGT_N = P * sizeof(int);

__global__ __launch_bounds__(256) void chan_stats_fb(
    const float* __restrict__ f, float* __restrict__ chan_off) {
  const int ch = blockIdx.x;
  const float4* base = (const float4*)(f + (size_t)ch * HW);
  const int n4 = HW / 4;
  float m = -FLT_MAX;
  for (int i = threadIdx.x; i < n4; i += 256) {
    float4 v = base[i];
    m = fmaxf(m, fmaxf(fmaxf(v.x, v.y), fmaxf(v.z, v.w)));
  }
  __shared__ float sred[4];
  __shared__ float bcast;
  const int wid = threadIdx.x >> 6, lid = threadIdx.x & 63;
  float wm = waveMax(m);
  if (lid == 0) sred[wid] = wm;
  __syncthreads();
  if (threadIdx.x == 0)
    bcast = fmaxf(fmaxf(sred[0], sred[1]), fmaxf(sred[2], sred[3]));
  __syncthreads();
  const float M = bcast;
  float s = 0.f;
  for (int i = threadIdx.x; i < n4; i += 256) {
    float4 v = base[i];
    s += __expf(v.x - M) + __expf(v.y - M) + __expf(v.z - M) + __expf(v.w - M);
  }
  float wsv = waveSum(s);
  __syncthreads();
  if (lid == 0) sred[wid] = wsv;
  __syncthreads();
  if (threadIdx.x == 0)
    chan_off[ch] = M + logf(sred[0] + sred[1] + sred[2] + sred[3]);
}

__global__ __launch_bounds__(256) void pixel_fb(
    const float* __restrict__ f, const int* __restrict__ target,
    const int* __restrict__ parcel, const float* __restrict__ chan_off,
    float* __restrict__ seg_sum, float* __restrict__ counts,
    int* __restrict__ tgtp, float* __restrict__ div_acc) {
  const int t4 = blockIdx.x * 256 + threadIdx.x;
  const int img = t4 / (HW / 4);
  const int pix0 = (t4 % (HW / 4)) * 4;
  const float* fb = f + (size_t)img * C * HW;
  __shared__ float soff[C];
  if (threadIdx.x < C) soff[threadIdx.x] = chan_off[img * C + threadIdx.x];
  __syncthreads();
  const int4 tv = *(const int4*)(target + (size_t)img * HW + pix0);
  const int4 pv = *(const int4*)(parcel + (size_t)img * HW + pix0);
  int tarr[4] = {tv.x, tv.y, tv.z, tv.w};
  int parr[4] = {pv.x, pv.y, pv.z, pv.w};
  bool val[4];
#pragma unroll
  for (int i = 0; i < 4; i++) val[i] = (tarr[i] != IGNORE_INDEX);
  float divs = 0.f;
#pragma unroll
  for (int k = 0; k < NC; k++) {
    float4 dmax = make_float4(-FLT_MAX, -FLT_MAX, -FLT_MAX, -FLT_MAX);
    float4 em = make_float4(-FLT_MAX, -FLT_MAX, -FLT_MAX, -FLT_MAX);
#pragma unroll
    for (int j = 0; j < CNUM; j++) {
      const int ch = k * CNUM + j;
      float4 v = *(const float4*)(fb + (size_t)ch * HW + pix0);
      const float off = soff[ch];
      dmax.x = fmaxf(dmax.x, v.x); dmax.y = fmaxf(dmax.y, v.y);
      dmax.z = fmaxf(dmax.z, v.z); dmax.w = fmaxf(dmax.w, v.w);
      em.x = fmaxf(em.x, v.x - off); em.y = fmaxf(em.y, v.y - off);
      em.z = fmaxf(em.z, v.z - off); em.w = fmaxf(em.w, v.w - off);
    }
    divs += __expf(em.x) + __expf(em.y) + __expf(em.z) + __expf(em.w);
    float dmv[4] = {dmax.x, dmax.y, dmax.z, dmax.w};
#pragma unroll
    for (int i = 0; i < 4; i++)
      if (val[i]) atomicAdd(&seg_sum[parr[i] * NC + k], dmv[i]);
  }
#pragma unroll
  for (int i = 0; i < 4; i++) {
    if (val[i]) {
      atomicAdd(&counts[parr[i]], 1.0f);
      atomicMax(&tgtp[parr[i]], tarr[i]);
    }
  }
  __shared__ float sred[4];
  const int wid = threadIdx.x >> 6, lid = threadIdx.x & 63;
  float wsum = waveSum(divs);
  if (lid == 0) sred[wid] = wsum;
  __syncthreads();
  if (threadIdx.x == 0)
    atomicAdd(div_acc, sred[0] + sred[1] + sred[2] + sred[3]);
}

__global__ __launch_bounds__(256) void seg_fb(
    const float* __restrict__ seg_sum, const float* __restrict__ counts,
    const int* __restrict__ tgtp, float* __restrict__ nll_acc,
    float* __restrict__ vcnt_acc) {
  const int s = blockIdx.x * 256 + threadIdx.x;
  const float cntv = counts[s];
  const float valid = (cntv > 0.f) ? 1.f : 0.f;
  const float inv = 1.f / fmaxf(cntv, 1.f);
  float mean[NC];
  float m = -FLT_MAX;
#pragma unroll
  for (int k = 0; k < NC; k++) {
    mean[k] = seg_sum[s * NC + k] * inv;
    m = fmaxf(m, mean[k]);
  }
  float se = 0.f;
#pragma unroll
  for (int k = 0; k < NC; k++) se += __expf(mean[k] - m);
  const float lse = m + logf(se);
  int t = tgtp[s];
  t = min(max(t, 0), NC - 1);
  const float nll = (lse - mean[t]) * valid;
  __shared__ float sn[4], sv[4];
  const int wid = threadIdx.x >> 6, lid = threadIdx.x & 63;
  float wn = waveSum(nll);
  float wv = waveSum(valid);
  if (lid == 0) { sn[wid] = wn; sv[wid] = wv; }
  __syncthreads();
  if (threadIdx.x == 0) {
    atomicAdd(nll_acc, sn[0] + sn[1] + sn[2] + sn[3]);
    atomicAdd(vcnt_acc, sv[0] + sv[1] + sv[2] + sv[3]);
  }
}

// ================= launch =================
extern "C" void kernel_launch(void* const* d_in, const int* in_sizes, int n_in,
                              void* d_out, int out_size, void* d_ws,
                              size_t ws_size, hipStream_t stream) {
  const float* features = (const float*)d_in[0];
  const int*   target   = (const int*)d_in[1];
  const int*   parcel   = (const int*)d_in[2];
  float* out = (float*)d_out;
  char* wsb = (char*)d_ws;

  if (ws_size >= NEED) {
    float* dmall = (float*)(wsb + B_DM);
    int*   sidx  = (int*)(wsb + B_SIDX);
    int*   cnt   = (int*)(wsb + B_CNT);
    float* acc   = (float*)(wsb + B_ACC);  // [div, nll, vcnt]
    int*   offs  = (int*)(wsb + B_OFF);
    int*   woff  = (int*)(wsb + B_WOFF);
    float* pm    = (float*)(wsb + B_PM);
    float* ps    = (float*)(wsb + B_PS);
    float* choff = (float*)(wsb + B_CHOFF);
    int*   tgtp  = (int*)(wsb + B_TGT);

    hipMemsetAsync(wsb + B_CNT, 0, P * 4 + 64, stream);  // cnt + acc

    stats_hist_kernel<<<NCH * STRIPES + NPIX / 1024, 256, 0, stream>>>(
        features, target, parcel, pm, ps, cnt);
    combine_scan_kernel<<<1, 1024, 0, stream>>>(pm, ps, choff, cnt, offs,
                                                woff);
    divbd_scatter_kernel<<<NPIX / 4 / 256, 256, 0, stream>>>(
        features, target, parcel, choff, woff, dmall, sidx, tgtp, acc + 0);
    parcel_kernel<<<P / 4, 256, 0, stream>>>(dmall, cnt, offs, sidx, tgtp,
                                             acc);
    finalize_kernel<<<1, 1, 0, stream>>>(acc, out);
  } else {
    float* ws       = (float*)d_ws;
    float* seg_sum  = ws + OFF_SEGSUM;
    float* counts   = ws + OFF_COUNTS;
    float* chan_off = ws + OFF_CHOFF;
    float* acc      = ws + OFF_ACC;
    int*   tgtp     = (int*)(wsb + BYTE_TGT);

    hipMemsetAsync(d_ws, 0, BYTE_ZERO, stream);
    hipMemsetAsync(wsb + BYTE_TGT, 0xFF, BYTE_TGT_N, stream);
    chan_stats_fb<<<NCH, 256, 0, stream>>>(features, chan_off);
    pixel_fb<<<NPIX / 4 / 256, 256, 0, stream>>>(features, target, parcel,
                                                 chan_off, seg_sum, counts,
                                                 tgtp, acc + 0);
    seg_fb<<<P / 256, 256, 0, stream>>>(seg_sum, counts, tgtp, acc + 1,
                                        acc + 2);
    finalize_kernel<<<1, 1, 0, stream>>>(acc, out);
  }
}